// Round 1
// baseline (1127.684 us; speedup 1.0000x reference)
//
#include <hip/hip_runtime.h>

// Problem constants (reference: N=16384, NUM_IN=1024, NUM_OUT=256), but we
// read sizes from the harness to stay general.
//
// out[o] = act( sum_k iv[k] * W[in_idx[k], j] + bias[j] ),  j = out_idx[o]
// act: 0=identity, 1=relu, 2=softsign
//
// input_indices are unique (arange) so the scatter == weighted row-sum.

__global__ __launch_bounds__(256) void sparse_gemv_kernel(
    const float* __restrict__ iv,      // [num_in]
    const float* __restrict__ W,       // [N, N] row-major
    const float* __restrict__ bias,    // [N]
    const int*   __restrict__ act,     // [N]
    const int*   __restrict__ in_idx,  // [num_in]
    const int*   __restrict__ out_idx, // [num_out]
    float*       __restrict__ out,     // [num_out]
    int N, int num_in)
{
    const int o = blockIdx.x;
    const int j = out_idx[o];
    const int tid = threadIdx.x;

    float sum = 0.0f;
    // num_in = 1024, blockDim = 256 -> 4 iterations per thread.
    for (int k = tid; k < num_in; k += blockDim.x) {
        const int row = in_idx[k];
        sum += iv[k] * W[(size_t)row * (size_t)N + (size_t)j];
    }

    // Wave (64-lane) shuffle reduction.
    #pragma unroll
    for (int off = 32; off > 0; off >>= 1)
        sum += __shfl_down(sum, off, 64);

    // Cross-wave reduction via LDS (4 waves in a 256-thread block).
    __shared__ float wsum[4];
    const int wave = tid >> 6;
    const int lane = tid & 63;
    if (lane == 0) wsum[wave] = sum;
    __syncthreads();

    if (tid == 0) {
        float t = wsum[0] + wsum[1] + wsum[2] + wsum[3] + bias[j];
        const int a = act[j];
        const float r = fmaxf(t, 0.0f);
        const float s = t / (1.0f + fabsf(t));
        out[o] = (a == 1) ? r : ((a == 2) ? s : t);
    }
}

extern "C" void kernel_launch(void* const* d_in, const int* in_sizes, int n_in,
                              void* d_out, int out_size, void* d_ws, size_t ws_size,
                              hipStream_t stream) {
    const float* iv      = (const float*)d_in[0];  // input_values   [num_in]
    const float* W       = (const float*)d_in[1];  // weight_matrix  [N*N]
    const float* bias    = (const float*)d_in[2];  // biases         [N]
    const int*   act     = (const int*)  d_in[3];  // act_ids        [N]
    const int*   in_idx  = (const int*)  d_in[4];  // input_indices  [num_in]
    const int*   out_idx = (const int*)  d_in[5];  // output_indices [num_out]
    float*       out     = (float*)d_out;

    const int num_in  = in_sizes[0];
    const int N       = in_sizes[2];   // biases length
    const int num_out = out_size;

    sparse_gemv_kernel<<<num_out, 256, 0, stream>>>(
        iv, W, bias, act, in_idx, out_idx, out, N, num_in);
}